// Round 10
// baseline (29108.514 us; speedup 1.0000x reference)
//
#include <hip/hip_runtime.h>

// InteractionGNN on MI355X — Round 10: R9-proven fp32 pipeline, telemetry
// stripped (graph-replay tripwire compliance: identical work every call).
// Inputs/weights fp32, edge_index int64 (runtime-detected), output fp32.
// Internal: h,e stored bf16 (absmax 3.9e-3 proven in R9), msg fp32.
// ws layout: flag | h bf16 | e bf16 | msg fp32 | stage fp32  (~233 MB).

#define TPB 256
constexpr int D    = 128;
constexpr int TILE = 32;
constexpr int NN   = 100000;
constexpr int NE   = 600000;

typedef unsigned short u16;

__device__ inline float bf2f(u16 x) { return __uint_as_float((unsigned)x << 16); }
__device__ inline float4 bf4_to_f4(ushort4 u) {
    float4 r;
    r.x = bf2f(u.x); r.y = bf2f(u.y); r.z = bf2f(u.z); r.w = bf2f(u.w);
    return r;
}
__device__ inline u16 f2bf(float f) {   // round-to-nearest-even
    unsigned u = __float_as_uint(f);
    unsigned r = u + 0x7FFFu + ((u >> 16) & 1u);
    return (u16)(r >> 16);
}
__device__ inline float4 ld4h(const u16* p) { return bf4_to_f4(*(const ushort4*)p); }
__device__ inline void   st4h(u16* p, float4 v) {
    ushort4 u; u.x = f2bf(v.x); u.y = f2bf(v.y); u.z = f2bf(v.z); u.w = f2bf(v.w);
    *(ushort4*)p = u;
}

__device__ inline int load_idx(const int* ei, long pos, int is64) {
    int v = is64 ? ei[2 * pos] : ei[pos];
    return (v < 0) ? 0 : (v >= NN ? NN - 1 : v);
}

// ---------------------------------------------------------------------------
// MLP tile body. fp32 weights/biases; h/e stored bf16 in ws; msg fp32.
// MODE: 0 node-enc (K=16, xf=nodes fp32)    | 1 edge-enc (K=256, gather h)
//       2 node-upd (K=256, h + msg fp32, +h)| 3 edge-upd (K=384, h,h,e, +e)
//       4 decoder  (K=384, layer2 128->1, fp32 out)
// ---------------------------------------------------------------------------
template<int K, int MODE>
__device__ inline void mlp_body(const u16* hbuf, const u16* ebuf, const float* xf,
                                const int* ei, const int* idxFlag,
                                const float* W1, const float* b1,
                                const float* W2, const float* b2, void* outv)
{
    constexpr int CHUNK = (K >= 32) ? 32 : K;
    constexpr int NCH   = K / CHUNK;
    constexpr int F4R   = CHUNK / 4;
    constexpr int HS_LD = 132;

    __shared__ float Xc[TILE * 32];       // 4 KB
    __shared__ float Ws[32 * 128];        // 16 KB
    __shared__ float Hs[TILE * HS_LD];    // 16.9 KB
    __shared__ float part[256];           // 1 KB
    __shared__ int   sIdx[TILE];
    __shared__ int   tIdx[TILE];

    const int  tid   = threadIdx.x;
    const long tile0 = (long)blockIdx.x * TILE;

    if (MODE == 1 || MODE == 3 || MODE == 4) {
        const int is64 = idxFlag[0];
        if (tid < TILE) {
            sIdx[tid] = load_idx(ei, tile0 + tid, is64);
        } else if (tid < 2 * TILE) {
            int r = tid - TILE;
            tIdx[r] = load_idx(ei, (long)NE + tile0 + r, is64);
        }
    }

    const int c  = tid & 31;
    const int r0 = (tid >> 5) * 4;
    const int j0 = c * 4;

    // ---------- layer 1: hidden = relu(X @ W1 + b1) ----------
    float acc[4][4];
    {
        float4 bv = *(const float4*)&b1[j0];
        #pragma unroll
        for (int i = 0; i < 4; ++i) { acc[i][0]=bv.x; acc[i][1]=bv.y; acc[i][2]=bv.z; acc[i][3]=bv.w; }
    }

    for (int ch = 0; ch < NCH; ++ch) {
        __syncthreads();
        for (int f = tid; f < TILE * F4R; f += TPB) {
            int  r   = f / F4R;
            int  kk4 = f % F4R;
            int  k   = ch * CHUNK + kk4 * 4;
            long row = tile0 + r;
            float4 v;
            if (MODE == 0) {
                v = *(const float4*)&xf[row * 16 + k];
            } else if (MODE == 1) {
                v = (k < D) ? ld4h(&hbuf[(long)sIdx[r] * D + k])
                            : ld4h(&hbuf[(long)tIdx[r] * D + (k - D)]);
            } else if (MODE == 2) {
                v = (k < D) ? ld4h(&hbuf[row * D + k])
                            : *(const float4*)&xf[row * D + (k - D)];
            } else {
                v = (k < D)     ? ld4h(&hbuf[(long)sIdx[r] * D + k])
                  : (k < 2 * D) ? ld4h(&hbuf[(long)tIdx[r] * D + (k - D)])
                                : ld4h(&ebuf[row * D + (k - 2 * D)]);
            }
            *(float4*)&Xc[r * CHUNK + kk4 * 4] = v;
        }
        for (int f = tid; f < CHUNK * 32; f += TPB) {
            int kk = f >> 5, j4 = f & 31;
            *(float4*)&Ws[kk * 128 + j4 * 4] =
                *(const float4*)&W1[(long)(ch * CHUNK + kk) * 128 + j4 * 4];
        }
        __syncthreads();
        #pragma unroll
        for (int kk = 0; kk < CHUNK; kk += 4) {
            float4 xv[4], wv[4];
            #pragma unroll
            for (int i = 0; i < 4; ++i) xv[i] = *(const float4*)&Xc[(r0 + i) * CHUNK + kk];
            #pragma unroll
            for (int m = 0; m < 4; ++m) wv[m] = *(const float4*)&Ws[(kk + m) * 128 + j0];
            #pragma unroll
            for (int i = 0; i < 4; ++i) {
                acc[i][0] += xv[i].x*wv[0].x + xv[i].y*wv[1].x + xv[i].z*wv[2].x + xv[i].w*wv[3].x;
                acc[i][1] += xv[i].x*wv[0].y + xv[i].y*wv[1].y + xv[i].z*wv[2].y + xv[i].w*wv[3].y;
                acc[i][2] += xv[i].x*wv[0].z + xv[i].y*wv[1].z + xv[i].z*wv[2].z + xv[i].w*wv[3].z;
                acc[i][3] += xv[i].x*wv[0].w + xv[i].y*wv[1].w + xv[i].z*wv[2].w + xv[i].w*wv[3].w;
            }
        }
    }

    #pragma unroll
    for (int i = 0; i < 4; ++i) {
        float4 hv;
        hv.x = fmaxf(acc[i][0], 0.f);
        hv.y = fmaxf(acc[i][1], 0.f);
        hv.z = fmaxf(acc[i][2], 0.f);
        hv.w = fmaxf(acc[i][3], 0.f);
        *(float4*)&Hs[(r0 + i) * HS_LD + j0] = hv;
    }

    // ---------- layer 2 ----------
    if (MODE == 4) {               // 128 -> 1 head, fp32 out
        __syncthreads();
        int row = tid & 31, seg = tid >> 5;
        float s = 0.f;
        #pragma unroll
        for (int k = 0; k < 16; ++k)
            s += Hs[row * HS_LD + seg * 16 + k] * W2[seg * 16 + k];
        part[seg * 32 + row] = s;
        __syncthreads();
        if (tid < 32) {
            float tot = b2[0];
            #pragma unroll
            for (int sg = 0; sg < 8; ++sg) tot += part[sg * 32 + tid];
            ((float*)outv)[tile0 + tid] = tot;
        }
        return;
    }

    u16* out = (u16*)outv;
    float acc2[4][4];
    {
        float4 bv = *(const float4*)&b2[j0];
        #pragma unroll
        for (int i = 0; i < 4; ++i) { acc2[i][0]=bv.x; acc2[i][1]=bv.y; acc2[i][2]=bv.z; acc2[i][3]=bv.w; }
    }
    #pragma unroll
    for (int ch = 0; ch < 4; ++ch) {
        __syncthreads();
        for (int f = tid; f < 32 * 32; f += TPB) {
            int kk = f >> 5, j4 = f & 31;
            *(float4*)&Ws[kk * 128 + j4 * 4] =
                *(const float4*)&W2[(long)(ch * 32 + kk) * 128 + j4 * 4];
        }
        __syncthreads();
        #pragma unroll
        for (int kk = 0; kk < 32; kk += 4) {
            float4 xv[4], wv[4];
            #pragma unroll
            for (int i = 0; i < 4; ++i) xv[i] = *(const float4*)&Hs[(r0 + i) * HS_LD + ch * 32 + kk];
            #pragma unroll
            for (int m = 0; m < 4; ++m) wv[m] = *(const float4*)&Ws[(kk + m) * 128 + j0];
            #pragma unroll
            for (int i = 0; i < 4; ++i) {
                acc2[i][0] += xv[i].x*wv[0].x + xv[i].y*wv[1].x + xv[i].z*wv[2].x + xv[i].w*wv[3].x;
                acc2[i][1] += xv[i].x*wv[0].y + xv[i].y*wv[1].y + xv[i].z*wv[2].y + xv[i].w*wv[3].y;
                acc2[i][2] += xv[i].x*wv[0].z + xv[i].y*wv[1].z + xv[i].z*wv[2].z + xv[i].w*wv[3].z;
                acc2[i][3] += xv[i].x*wv[0].w + xv[i].y*wv[1].w + xv[i].z*wv[2].w + xv[i].w*wv[3].w;
            }
        }
    }

    #pragma unroll
    for (int i = 0; i < 4; ++i) {
        long row = tile0 + r0 + i;
        float4 o;
        o.x = acc2[i][0]; o.y = acc2[i][1]; o.z = acc2[i][2]; o.w = acc2[i][3];
        if (MODE == 2) {
            float4 res = ld4h(&hbuf[row * D + j0]);
            o.x += res.x; o.y += res.y; o.z += res.z; o.w += res.w;
        } else if (MODE == 3) {
            float4 res = ld4h(&ebuf[row * D + j0]);
            o.x += res.x; o.y += res.y; o.z += res.z; o.w += res.w;
        }
        st4h(&out[row * D + j0], o);
    }
}

// --------------------------- plain kernel symbols ---------------------------

__global__ void k_detect(const int* __restrict__ ei, int* __restrict__ flag) {
    if (threadIdx.x == 0 && blockIdx.x == 0) {
        int any = 0;
        for (int i = 0; i < 64; ++i) any |= ei[2 * i + 1];
        flag[0] = (any == 0) ? 1 : 0;
    }
}

__launch_bounds__(TPB)
__global__ void k_node_enc(const float* nodes, const float* W1, const float* b1,
                           const float* W2, const float* b2, u16* h) {
    mlp_body<16, 0>(nullptr, nullptr, nodes, nullptr, nullptr, W1, b1, W2, b2, h);
}

__launch_bounds__(TPB)
__global__ void k_edge_enc(const u16* h, const int* ei, const int* flag,
                           const float* W1, const float* b1,
                           const float* W2, const float* b2, u16* e) {
    mlp_body<256, 1>(h, nullptr, nullptr, ei, flag, W1, b1, W2, b2, e);
}

__launch_bounds__(TPB)
__global__ void k_node_upd(const u16* h, const float* msg,
                           const float* W1, const float* b1,
                           const float* W2, const float* b2, u16* hout) {
    mlp_body<256, 2>(h, nullptr, msg, nullptr, nullptr, W1, b1, W2, b2, hout);
}

__launch_bounds__(TPB)
__global__ void k_edge_upd(const u16* h, const u16* e, const int* ei, const int* flag,
                           const float* W1, const float* b1,
                           const float* W2, const float* b2, u16* eout) {
    mlp_body<384, 3>(h, e, nullptr, ei, flag, W1, b1, W2, b2, eout);
}

__launch_bounds__(TPB)
__global__ void k_decode(const u16* h, const u16* e, const int* ei, const int* flag,
                         const float* W1, const float* b1,
                         const float* W2, const float* b2, float* pred) {
    mlp_body<384, 4>(h, e, nullptr, ei, flag, W1, b1, W2, b2, pred);
}

__global__ void k_scatter(const u16* __restrict__ e, const int* __restrict__ ei,
                          const int* __restrict__ idxFlag, float* __restrict__ msg)
{
    long gid  = (long)blockIdx.x * blockDim.x + threadIdx.x;
    int  edge = (int)(gid >> 7);
    int  j    = (int)(gid & 127);
    int  n    = load_idx(ei, (long)NE + edge, idxFlag[0]);
    atomicAdd(&msg[(long)n * D + j], bf2f(e[(long)edge * D + j]));
}

// ---------------------------------------------------------------------------

extern "C" void kernel_launch(void* const* d_in, const int* in_sizes, int n_in,
                              void* d_out, int out_size, void* d_ws, size_t ws_size,
                              hipStream_t stream)
{
    const float* nodes = (const float*)d_in[0];
    const int*   ei    = (const int*)d_in[1];
    const float* ne_W1 = (const float*)d_in[2];  const float* ne_b1 = (const float*)d_in[3];
    const float* ne_W2 = (const float*)d_in[4];  const float* ne_b2 = (const float*)d_in[5];
    const float* ee_W1 = (const float*)d_in[6];  const float* ee_b1 = (const float*)d_in[7];
    const float* ee_W2 = (const float*)d_in[8];  const float* ee_b2 = (const float*)d_in[9];
    const float* nn_W1 = (const float*)d_in[10]; const float* nn_b1 = (const float*)d_in[11];
    const float* nn_W2 = (const float*)d_in[12]; const float* nn_b2 = (const float*)d_in[13];
    const float* en_W1 = (const float*)d_in[14]; const float* en_b1 = (const float*)d_in[15];
    const float* en_W2 = (const float*)d_in[16]; const float* en_b2 = (const float*)d_in[17];
    const float* pe_W1 = (const float*)d_in[18]; const float* pe_b1 = (const float*)d_in[19];
    const float* pe_W2 = (const float*)d_in[20]; const float* pe_b2 = (const float*)d_in[21];

    const size_t hN = (size_t)NN * D;   // 12.8M elems
    const size_t eN = (size_t)NE * D;   // 76.8M elems
    const size_t need = 256 + hN * 2 + eN * 2 + hN * 4 + (size_t)NE * 4; // ~233 MB
    if (ws_size < need) {   // constant per session; same branch every call
        hipMemsetAsync(d_out, 0x43, (size_t)out_size * sizeof(float), stream);
        return;
    }

    int*   flag  = (int*)d_ws;
    u16*   h     = (u16*)((char*)d_ws + 256);
    u16*   e     = h + hN;
    float* msg   = (float*)(e + eN);
    float* stage = msg + hN;

    dim3 blk(TPB);
    k_detect<<<1, 64, 0, stream>>>(ei, flag);
    k_node_enc<<<NN / TILE, blk, 0, stream>>>(nodes, ne_W1, ne_b1, ne_W2, ne_b2, h);
    k_edge_enc<<<NE / TILE, blk, 0, stream>>>(h, ei, flag, ee_W1, ee_b1, ee_W2, ee_b2, e);

    for (int it = 0; it < 4; ++it) {
        hipMemsetAsync(msg, 0, hN * sizeof(float), stream);
        k_scatter<<<(int)((long)NE * D / TPB), blk, 0, stream>>>(e, ei, flag, msg);
        // e <- MLP_en([h_old[s], h_old[t], e_old]) + e_old   (uses pre-update h)
        k_edge_upd<<<NE / TILE, blk, 0, stream>>>(h, e, ei, flag,
                                                  en_W1, en_b1, en_W2, en_b2, e);
        // h <- MLP_nn([h_old, msg]) + h_old
        k_node_upd<<<NN / TILE, blk, 0, stream>>>(h, msg,
                                                  nn_W1, nn_b1, nn_W2, nn_b2, h);
    }

    k_decode<<<NE / TILE, blk, 0, stream>>>(h, e, ei, flag,
                                            pe_W1, pe_b1, pe_W2, pe_b2, stage);
    hipMemcpyAsync(d_out, stage, (size_t)NE * sizeof(float),
                   hipMemcpyDeviceToDevice, stream);
}

// Round 11
// 3556.684 us; speedup vs baseline: 8.1842x; 8.1842x over previous
//
#include <hip/hip_runtime.h>

// InteractionGNN on MI355X — Round 11: MFMA bf16 for the heavy MLPs.
// Proven-correct R10 pipeline; edge_enc/edge_upd/node_upd/decode now use
// v_mfma_f32_16x16x32_bf16 with 128x128 block tiles (wave tile 64x64).
// Weights pre-converted once per call to chunk-blocked transposed bf16 in ws.
// ws: flag | h bf16 | e bf16 | msg fp32 (stage fp32 overlaps msg) | Wt blocks.

#define TPB 256
constexpr int D    = 128;
constexpr int TILE = 32;
constexpr int NN   = 100000;
constexpr int NE   = 600000;

typedef unsigned short u16;
typedef __attribute__((ext_vector_type(8))) short bf16x8;   // 8 bf16 = 4 VGPR
typedef __attribute__((ext_vector_type(4))) float f32x4;

__device__ inline float bf2f(u16 x) { return __uint_as_float((unsigned)x << 16); }
__device__ inline float4 bf4_to_f4(ushort4 u) {
    float4 r;
    r.x = bf2f(u.x); r.y = bf2f(u.y); r.z = bf2f(u.z); r.w = bf2f(u.w);
    return r;
}
__device__ inline u16 f2bf(float f) {   // round-to-nearest-even
    unsigned u = __float_as_uint(f);
    unsigned r = u + 0x7FFFu + ((u >> 16) & 1u);
    return (u16)(r >> 16);
}
__device__ inline float4 ld4h(const u16* p) { return bf4_to_f4(*(const ushort4*)p); }
__device__ inline void   st4h(u16* p, float4 v) {
    ushort4 u; u.x = f2bf(v.x); u.y = f2bf(v.y); u.z = f2bf(v.z); u.w = f2bf(v.w);
    *(ushort4*)p = u;
}
__device__ inline int load_idx(const int* ei, long pos, int is64) {
    int v = is64 ? ei[2 * pos] : ei[pos];
    return (v < 0) ? 0 : (v >= NN ? NN - 1 : v);
}

// ---------------------------------------------------------------------------
// MFMA MLP body. Block tile M=128 x N=128; 4 waves in 2x2; wave tile 64x64.
// Per K-32 chunk per wave: 4 A-frags + 4 B-frags (ds_read_b128) + 16 MFMA.
// MODE: 1 edge-enc (K=256, X=[h_s,h_t])      | 2 node-upd (K=256, X=[h,msg], +h)
//       3 edge-upd (K=384, X=[h_s,h_t,e], +e)| 4 decoder  (K=384, layer2 128->1)
// W1t/W2t: chunk-blocked transposed bf16 [ch][n=128][k=40pad].
// ---------------------------------------------------------------------------
template<int K, int MODE>
__device__ inline void mfma_mlp(const u16* hbuf, const u16* ebuf, const float* msg,
                                const int* ei, const int* idxFlag,
                                const u16* W1t, const float* b1,
                                const u16* W2t, const float* w2orb2,
                                const float* bias2, void* outp)
{
    constexpr int NCH   = K / 32;
    constexpr long NROWS = (MODE == 2) ? NN : NE;

    __shared__ alignas(16) u16 Xs[128 * 40];    // 10.2 KB
    __shared__ alignas(16) u16 Ws[128 * 40];    // 10.2 KB
    __shared__ alignas(16) u16 Hs[128 * 136];   // 34.8 KB
    __shared__ int   sIdx[128];
    __shared__ int   tIdx[128];
    __shared__ float part[256];
    __shared__ float w2s[128];

    const int tid  = threadIdx.x;
    const int lane = tid & 63;
    const int wave = tid >> 6;
    const int wm   = wave >> 1;      // 0..1: m-half (64 rows)
    const int wn   = wave & 1;       // 0..1: n-half (64 cols)
    const int lr   = lane & 15;
    const int lq   = lane >> 4;
    const long tile0 = (long)blockIdx.x * 128;

    if (MODE != 2) {
        const int is64 = idxFlag[0];
        if (tid < 128) {
            long p = tile0 + tid; if (p > NE - 1) p = NE - 1;
            sIdx[tid] = load_idx(ei, p, is64);
        } else {
            int r = tid - 128;
            long p = tile0 + r; if (p > NE - 1) p = NE - 1;
            tIdx[r] = load_idx(ei, (long)NE + p, is64);
        }
    }
    if (MODE == 4 && tid < 128) w2s[tid] = w2orb2[tid];

    // ---------------- layer 1 ----------------
    f32x4 acc[4][4];
    #pragma unroll
    for (int nt = 0; nt < 4; ++nt) {
        float bv = b1[wn * 64 + nt * 16 + lr];
        #pragma unroll
        for (int mt = 0; mt < 4; ++mt) acc[mt][nt] = (f32x4){bv, bv, bv, bv};
    }

    for (int ch = 0; ch < NCH; ++ch) {
        __syncthreads();
        // stage Xs: 128 rows x 32 bf16 (gather-concat per MODE)
        #pragma unroll
        for (int f = tid; f < 512; f += TPB) {
            int  r = f >> 2, q = f & 3;
            int  k = ch * 32 + q * 8;
            long row = tile0 + r; if (row > NROWS - 1) row = NROWS - 1;
            uint4 v;
            if (MODE == 2) {
                if (k < D) {
                    v = *(const uint4*)&hbuf[row * D + k];
                } else {
                    const float* s = &msg[row * D + (k - D)];
                    float4 f0 = *(const float4*)s;
                    float4 f1 = *(const float4*)(s + 4);
                    alignas(16) u16 t[8];
                    t[0]=f2bf(f0.x); t[1]=f2bf(f0.y); t[2]=f2bf(f0.z); t[3]=f2bf(f0.w);
                    t[4]=f2bf(f1.x); t[5]=f2bf(f1.y); t[6]=f2bf(f1.z); t[7]=f2bf(f1.w);
                    v = *(const uint4*)t;
                }
            } else {
                const u16* s = (k < D)     ? &hbuf[(long)sIdx[r] * D + k]
                             : (k < 2 * D) ? &hbuf[(long)tIdx[r] * D + (k - D)]
                                           : &ebuf[row * D + (k - 2 * D)];
                v = *(const uint4*)s;
            }
            *(uint4*)&Xs[r * 40 + q * 8] = v;
        }
        // stage W1 chunk (pre-blocked: flat 10240 B copy)
        {
            const uint4* src = (const uint4*)(W1t + (size_t)ch * 5120);
            uint4* dst = (uint4*)Ws;
            for (int f = tid; f < 640; f += TPB) dst[f] = src[f];
        }
        __syncthreads();

        bf16x8 a[4], b[4];
        #pragma unroll
        for (int mt = 0; mt < 4; ++mt)
            a[mt] = *(const bf16x8*)&Xs[(wm * 64 + mt * 16 + lr) * 40 + lq * 8];
        #pragma unroll
        for (int nt = 0; nt < 4; ++nt)
            b[nt] = *(const bf16x8*)&Ws[(wn * 64 + nt * 16 + lr) * 40 + lq * 8];
        #pragma unroll
        for (int mt = 0; mt < 4; ++mt)
            #pragma unroll
            for (int nt = 0; nt < 4; ++nt)
                acc[mt][nt] = __builtin_amdgcn_mfma_f32_16x16x32_bf16(
                                  a[mt], b[nt], acc[mt][nt], 0, 0, 0);
    }

    // relu -> Hs (C layout: col=lane&15, row=(lane>>4)*4+reg)
    #pragma unroll
    for (int mt = 0; mt < 4; ++mt)
        #pragma unroll
        for (int nt = 0; nt < 4; ++nt)
            #pragma unroll
            for (int reg = 0; reg < 4; ++reg) {
                int row = wm * 64 + mt * 16 + lq * 4 + reg;
                int col = wn * 64 + nt * 16 + lr;
                Hs[row * 136 + col] = f2bf(fmaxf(acc[mt][nt][reg], 0.f));
            }
    __syncthreads();

    // ---------------- layer 2 ----------------
    if (MODE == 4) {               // 128 -> 1 head: VALU dot from Hs
        float s = 0.f;
        int r = tid >> 1, k0 = (tid & 1) * 64;
        #pragma unroll
        for (int j = 0; j < 64; ++j)
            s += bf2f(Hs[r * 136 + k0 + j]) * w2s[k0 + j];
        part[tid] = s;
        __syncthreads();
        if (tid < 128) {
            long row = tile0 + tid;
            if (row < NROWS)
                ((float*)outp)[row] = part[tid * 2] + part[tid * 2 + 1] + bias2[0];
        }
        return;
    }

    f32x4 acc2[4][4];
    #pragma unroll
    for (int nt = 0; nt < 4; ++nt) {
        float bv = w2orb2[wn * 64 + nt * 16 + lr];
        #pragma unroll
        for (int mt = 0; mt < 4; ++mt) acc2[mt][nt] = (f32x4){bv, bv, bv, bv};
    }
    for (int ch = 0; ch < 4; ++ch) {
        __syncthreads();
        {
            const uint4* src = (const uint4*)(W2t + (size_t)ch * 5120);
            uint4* dst = (uint4*)Ws;
            for (int f = tid; f < 640; f += TPB) dst[f] = src[f];
        }
        __syncthreads();
        bf16x8 a[4], b[4];
        #pragma unroll
        for (int mt = 0; mt < 4; ++mt)
            a[mt] = *(const bf16x8*)&Hs[(wm * 64 + mt * 16 + lr) * 136 + ch * 32 + lq * 8];
        #pragma unroll
        for (int nt = 0; nt < 4; ++nt)
            b[nt] = *(const bf16x8*)&Ws[(wn * 64 + nt * 16 + lr) * 40 + lq * 8];
        #pragma unroll
        for (int mt = 0; mt < 4; ++mt)
            #pragma unroll
            for (int nt = 0; nt < 4; ++nt)
                acc2[mt][nt] = __builtin_amdgcn_mfma_f32_16x16x32_bf16(
                                   a[mt], b[nt], acc2[mt][nt], 0, 0, 0);
    }
    __syncthreads();
    #pragma unroll
    for (int mt = 0; mt < 4; ++mt)
        #pragma unroll
        for (int nt = 0; nt < 4; ++nt)
            #pragma unroll
            for (int reg = 0; reg < 4; ++reg) {
                int row = wm * 64 + mt * 16 + lq * 4 + reg;
                int col = wn * 64 + nt * 16 + lr;
                Hs[row * 136 + col] = f2bf(acc2[mt][nt][reg]);
            }
    __syncthreads();

    // residual + coalesced store (16 bf16 per thread-iter)
    u16* out = (u16*)outp;
    #pragma unroll
    for (int f = tid; f < 1024; f += TPB) {
        int r = f >> 3, q = f & 7;
        long row = tile0 + r;
        if (row >= NROWS) continue;
        int col = q * 16;
        const u16* hp = &Hs[r * 136 + col];
        const u16* res = (MODE == 3) ? &ebuf[row * D + col] : &hbuf[row * D + col];
        alignas(16) u16 ov[16];
        #pragma unroll
        for (int j = 0; j < 16; ++j) {
            float v = bf2f(hp[j]);
            if (MODE != 1) v += bf2f(res[j]);
            ov[j] = f2bf(v);
        }
        *(uint4*)&out[row * D + col]     = *(const uint4*)&ov[0];
        *(uint4*)&out[row * D + col + 8] = *(const uint4*)&ov[8];
    }
}

// ---------------------------------------------------------------------------
// Old proven VALU MLP body — kept only for the tiny node encoder (K=16).
// ---------------------------------------------------------------------------
template<int K, int MODE>
__device__ inline void mlp_body(const u16* hbuf, const u16* ebuf, const float* xf,
                                const int* ei, const int* idxFlag,
                                const float* W1, const float* b1,
                                const float* W2, const float* b2, void* outv)
{
    constexpr int CHUNK = (K >= 32) ? 32 : K;
    constexpr int NCH   = K / CHUNK;
    constexpr int F4R   = CHUNK / 4;
    constexpr int HS_LD = 132;

    __shared__ float Xc[TILE * 32];
    __shared__ float Wsl[32 * 128];
    __shared__ float Hsl[TILE * HS_LD];

    const int  tid   = threadIdx.x;
    const long tile0 = (long)blockIdx.x * TILE;

    const int c  = tid & 31;
    const int r0 = (tid >> 5) * 4;
    const int j0 = c * 4;

    float acc[4][4];
    {
        float4 bv = *(const float4*)&b1[j0];
        #pragma unroll
        for (int i = 0; i < 4; ++i) { acc[i][0]=bv.x; acc[i][1]=bv.y; acc[i][2]=bv.z; acc[i][3]=bv.w; }
    }
    for (int ch = 0; ch < NCH; ++ch) {
        __syncthreads();
        for (int f = tid; f < TILE * F4R; f += TPB) {
            int  r   = f / F4R;
            int  kk4 = f % F4R;
            int  k   = ch * CHUNK + kk4 * 4;
            long row = tile0 + r;
            *(float4*)&Xc[r * CHUNK + kk4 * 4] = *(const float4*)&xf[row * 16 + k];
        }
        for (int f = tid; f < CHUNK * 32; f += TPB) {
            int kk = f >> 5, j4 = f & 31;
            *(float4*)&Wsl[kk * 128 + j4 * 4] =
                *(const float4*)&W1[(long)(ch * CHUNK + kk) * 128 + j4 * 4];
        }
        __syncthreads();
        #pragma unroll
        for (int kk = 0; kk < CHUNK; kk += 4) {
            float4 xv[4], wv[4];
            #pragma unroll
            for (int i = 0; i < 4; ++i) xv[i] = *(const float4*)&Xc[(r0 + i) * CHUNK + kk];
            #pragma unroll
            for (int m = 0; m < 4; ++m) wv[m] = *(const float4*)&Wsl[(kk + m) * 128 + j0];
            #pragma unroll
            for (int i = 0; i < 4; ++i) {
                acc[i][0] += xv[i].x*wv[0].x + xv[i].y*wv[1].x + xv[i].z*wv[2].x + xv[i].w*wv[3].x;
                acc[i][1] += xv[i].x*wv[0].y + xv[i].y*wv[1].y + xv[i].z*wv[2].y + xv[i].w*wv[3].y;
                acc[i][2] += xv[i].x*wv[0].z + xv[i].y*wv[1].z + xv[i].z*wv[2].z + xv[i].w*wv[3].z;
                acc[i][3] += xv[i].x*wv[0].w + xv[i].y*wv[1].w + xv[i].z*wv[2].w + xv[i].w*wv[3].w;
            }
        }
    }
    #pragma unroll
    for (int i = 0; i < 4; ++i) {
        float4 hv;
        hv.x = fmaxf(acc[i][0], 0.f);
        hv.y = fmaxf(acc[i][1], 0.f);
        hv.z = fmaxf(acc[i][2], 0.f);
        hv.w = fmaxf(acc[i][3], 0.f);
        *(float4*)&Hsl[(r0 + i) * HS_LD + j0] = hv;
    }
    float acc2[4][4];
    {
        float4 bv = *(const float4*)&b2[j0];
        #pragma unroll
        for (int i = 0; i < 4; ++i) { acc2[i][0]=bv.x; acc2[i][1]=bv.y; acc2[i][2]=bv.z; acc2[i][3]=bv.w; }
    }
    #pragma unroll
    for (int ch = 0; ch < 4; ++ch) {
        __syncthreads();
        for (int f = tid; f < 32 * 32; f += TPB) {
            int kk = f >> 5, j4 = f & 31;
            *(float4*)&Wsl[kk * 128 + j4 * 4] =
                *(const float4*)&W2[(long)(ch * 32 + kk) * 128 + j4 * 4];
        }
        __syncthreads();
        #pragma unroll
        for (int kk = 0; kk < 32; kk += 4) {
            float4 xv[4], wv[4];
            #pragma unroll
            for (int i = 0; i < 4; ++i) xv[i] = *(const float4*)&Hsl[(r0 + i) * HS_LD + ch * 32 + kk];
            #pragma unroll
            for (int m = 0; m < 4; ++m) wv[m] = *(const float4*)&Wsl[(kk + m) * 128 + j0];
            #pragma unroll
            for (int i = 0; i < 4; ++i) {
                acc2[i][0] += xv[i].x*wv[0].x + xv[i].y*wv[1].x + xv[i].z*wv[2].x + xv[i].w*wv[3].x;
                acc2[i][1] += xv[i].x*wv[0].y + xv[i].y*wv[1].y + xv[i].z*wv[2].y + xv[i].w*wv[3].y;
                acc2[i][2] += xv[i].x*wv[0].z + xv[i].y*wv[1].z + xv[i].z*wv[2].z + xv[i].w*wv[3].z;
                acc2[i][3] += xv[i].x*wv[0].w + xv[i].y*wv[1].w + xv[i].z*wv[2].w + xv[i].w*wv[3].w;
            }
        }
    }
    u16* out = (u16*)outv;
    #pragma unroll
    for (int i = 0; i < 4; ++i) {
        long row = tile0 + r0 + i;
        float4 o;
        o.x = acc2[i][0]; o.y = acc2[i][1]; o.z = acc2[i][2]; o.w = acc2[i][3];
        st4h(&out[row * D + j0], o);
    }
}

// --------------------------- plain kernel symbols ---------------------------

__global__ void k_detect(const int* __restrict__ ei, int* __restrict__ flag) {
    if (threadIdx.x == 0 && blockIdx.x == 0) {
        int any = 0;
        for (int i = 0; i < 64; ++i) any |= ei[2 * i + 1];
        flag[0] = (any == 0) ? 1 : 0;
    }
}

// convert W [K][128] fp32 -> chunk-blocked transposed bf16 [ch][n=128][k=40pad]
__global__ void k_prep(const float* __restrict__ W, u16* __restrict__ dst, int K) {
    int total = (K >> 5) * 5120;
    for (int i = blockIdx.x * TPB + threadIdx.x; i < total; i += gridDim.x * TPB) {
        int ch = i / 5120, rem = i % 5120;
        int n = rem / 40, kk = rem % 40;
        float v = (kk < 32) ? W[(size_t)(ch * 32 + kk) * 128 + n] : 0.f;
        dst[i] = f2bf(v);
    }
}

__launch_bounds__(TPB)
__global__ void k_node_enc(const float* nodes, const float* W1, const float* b1,
                           const float* W2, const float* b2, u16* h) {
    mlp_body<16, 0>(nullptr, nullptr, nodes, nullptr, nullptr, W1, b1, W2, b2, h);
}

__launch_bounds__(TPB)
__global__ void k_edge_enc_m(const u16* h, const int* ei, const int* flag,
                             const u16* W1t, const float* b1,
                             const u16* W2t, const float* b2, u16* e) {
    mfma_mlp<256, 1>(h, nullptr, nullptr, ei, flag, W1t, b1, W2t, b2, nullptr, e);
}

__launch_bounds__(TPB)
__global__ void k_node_upd_m(const u16* h, const float* msg,
                             const u16* W1t, const float* b1,
                             const u16* W2t, const float* b2, u16* hout) {
    mfma_mlp<256, 2>(h, nullptr, msg, nullptr, nullptr, W1t, b1, W2t, b2, nullptr, hout);
}

__launch_bounds__(TPB)
__global__ void k_edge_upd_m(const u16* h, const u16* e, const int* ei, const int* flag,
                             const u16* W1t, const float* b1,
                             const u16* W2t, const float* b2, u16* eout) {
    mfma_mlp<384, 3>(h, e, nullptr, ei, flag, W1t, b1, W2t, b2, nullptr, eout);
}

__launch_bounds__(TPB)
__global__ void k_decode_m(const u16* h, const u16* e, const int* ei, const int* flag,
                           const u16* W1t, const float* b1,
                           const float* w2, const float* b2, float* pred) {
    mfma_mlp<384, 4>(h, e, nullptr, ei, flag, W1t, b1, nullptr, w2, b2, pred);
}

__global__ void k_scatter(const u16* __restrict__ e, const int* __restrict__ ei,
                          const int* __restrict__ idxFlag, float* __restrict__ msg)
{
    long gid  = (long)blockIdx.x * blockDim.x + threadIdx.x;
    int  edge = (int)(gid >> 7);
    int  j    = (int)(gid & 127);
    int  n    = load_idx(ei, (long)NE + edge, idxFlag[0]);
    atomicAdd(&msg[(long)n * D + j], bf2f(e[(long)edge * D + j]));
}

// ---------------------------------------------------------------------------

extern "C" void kernel_launch(void* const* d_in, const int* in_sizes, int n_in,
                              void* d_out, int out_size, void* d_ws, size_t ws_size,
                              hipStream_t stream)
{
    const float* nodes = (const float*)d_in[0];
    const int*   ei    = (const int*)d_in[1];
    const float* ne_W1 = (const float*)d_in[2];  const float* ne_b1 = (const float*)d_in[3];
    const float* ne_W2 = (const float*)d_in[4];  const float* ne_b2 = (const float*)d_in[5];
    const float* ee_W1 = (const float*)d_in[6];  const float* ee_b1 = (const float*)d_in[7];
    const float* ee_W2 = (const float*)d_in[8];  const float* ee_b2 = (const float*)d_in[9];
    const float* nn_W1 = (const float*)d_in[10]; const float* nn_b1 = (const float*)d_in[11];
    const float* nn_W2 = (const float*)d_in[12]; const float* nn_b2 = (const float*)d_in[13];
    const float* en_W1 = (const float*)d_in[14]; const float* en_b1 = (const float*)d_in[15];
    const float* en_W2 = (const float*)d_in[16]; const float* en_b2 = (const float*)d_in[17];
    const float* pe_W1 = (const float*)d_in[18]; const float* pe_b1 = (const float*)d_in[19];
    const float* pe_W2 = (const float*)d_in[20]; const float* pe_b2 = (const float*)d_in[21];

    const size_t hN = (size_t)NN * D;   // 12.8M elems
    const size_t eN = (size_t)NE * D;   // 76.8M elems
    // blocked-weight sizes in u16 units (chunk = 128*40 = 5120 u16)
    const size_t W8  = 8  * 5120;       // K=256 layer1
    const size_t W12 = 12 * 5120;       // K=384 layer1
    const size_t W4  = 4  * 5120;       // K=128 layer2
    const size_t wTot = W8 * 2 + W12 * 2 + W4 * 3;
    const size_t need = 256 + hN * 2 + eN * 2 + hN * 4 + wTot * 2;  // ~231 MB

    if (ws_size < need) {   // constant per session
        hipMemsetAsync(d_out, 0x43, (size_t)out_size * sizeof(float), stream);
        return;
    }

    int*   flag  = (int*)d_ws;
    u16*   h     = (u16*)((char*)d_ws + 256);
    u16*   e     = h + hN;
    float* msg   = (float*)(e + eN);
    float* stage = msg;                         // overlaps msg (dead at decode)
    u16*   wbase = (u16*)(msg + hN);
    u16*   ee1t  = wbase;
    u16*   nn1t  = ee1t + W8;
    u16*   en1t  = nn1t + W8;
    u16*   pe1t  = en1t + W12;
    u16*   ee2t  = pe1t + W12;
    u16*   nn2t  = ee2t + W4;
    u16*   en2t  = nn2t + W4;

    dim3 blk(TPB);
    k_detect<<<1, 64, 0, stream>>>(ei, flag);

    k_prep<<<64, blk, 0, stream>>>(ee_W1, ee1t, 256);
    k_prep<<<64, blk, 0, stream>>>(nn_W1, nn1t, 256);
    k_prep<<<64, blk, 0, stream>>>(en_W1, en1t, 384);
    k_prep<<<64, blk, 0, stream>>>(pe_W1, pe1t, 384);
    k_prep<<<64, blk, 0, stream>>>(ee_W2, ee2t, 128);
    k_prep<<<64, blk, 0, stream>>>(nn_W2, nn2t, 128);
    k_prep<<<64, blk, 0, stream>>>(en_W2, en2t, 128);

    const int EG = (NE + 127) / 128;    // 4688
    const int NG = (NN + 127) / 128;    // 782

    k_node_enc<<<NN / TILE, blk, 0, stream>>>(nodes, ne_W1, ne_b1, ne_W2, ne_b2, h);
    k_edge_enc_m<<<EG, blk, 0, stream>>>(h, ei, flag, ee1t, ee_b1, ee2t, ee_b2, e);

    for (int it = 0; it < 4; ++it) {
        hipMemsetAsync(msg, 0, hN * sizeof(float), stream);
        k_scatter<<<(int)((long)NE * D / TPB), blk, 0, stream>>>(e, ei, flag, msg);
        // e <- MLP_en([h_old[s], h_old[t], e_old]) + e_old   (uses pre-update h)
        k_edge_upd_m<<<EG, blk, 0, stream>>>(h, e, ei, flag, en1t, en_b1, en2t, en_b2, e);
        // h <- MLP_nn([h_old, msg]) + h_old
        k_node_upd_m<<<NG, blk, 0, stream>>>(h, msg, nn1t, nn_b1, nn2t, nn_b2, h);
    }

    k_decode_m<<<EG, blk, 0, stream>>>(h, e, ei, flag, pe1t, pe_b1, pe_W2, pe_b2, stage);
    hipMemcpyAsync(d_out, stage, (size_t)NE * sizeof(float),
                   hipMemcpyDeviceToDevice, stream);
}

// Round 12
// 2387.358 us; speedup vs baseline: 12.1928x; 1.4898x over previous
//
#include <hip/hip_runtime.h>

// InteractionGNN on MI355X — Round 12: node_enc -> MFMA; atomic scatter ->
// CSR + per-wave gather-sum (no atomics in hot loop, no msg memsets).
// All five MLPs now use v_mfma_f32_16x16x32_bf16, 128x128 block tile,
// 2x2 waves of 64x64. Weights pre-blocked to [ch][n=128][k=40pad] bf16.
// ws: flag | h bf16 | e bf16 | msg f32 (stage overlaps) | Wt | CSR arrays.

#define TPB 256
constexpr int D    = 128;
constexpr int NN   = 100000;
constexpr int NE   = 600000;

typedef unsigned short u16;
typedef __attribute__((ext_vector_type(8))) short bf16x8;
typedef __attribute__((ext_vector_type(4))) float f32x4;

__device__ inline float bf2f(u16 x) { return __uint_as_float((unsigned)x << 16); }
__device__ inline u16 f2bf(float f) {   // round-to-nearest-even
    unsigned u = __float_as_uint(f);
    unsigned r = u + 0x7FFFu + ((u >> 16) & 1u);
    return (u16)(r >> 16);
}
__device__ inline int load_idx(const int* ei, long pos, int is64) {
    int v = is64 ? ei[2 * pos] : ei[pos];
    return (v < 0) ? 0 : (v >= NN ? NN - 1 : v);
}

// ---------------------------------------------------------------------------
// MFMA MLP body. Block tile M=128 x N=128; 4 waves 2x2; wave tile 64x64.
// MODE: 0 node-enc (K=32 padded, fin=nodes fp32[*,16])
//       1 edge-enc (K=256, X=[h_s,h_t])
//       2 node-upd (K=256, X=[h,msg fp32], +h residual)
//       3 edge-upd (K=384, X=[h_s,h_t,e], +e residual)
//       4 decoder  (K=384, layer2 128->1, fp32 out)
// ---------------------------------------------------------------------------
template<int K, int MODE>
__device__ inline void mfma_mlp(const u16* hbuf, const u16* ebuf, const float* fin,
                                const int* ei, const int* idxFlag,
                                const u16* W1t, const float* b1,
                                const u16* W2t, const float* w2orb2,
                                const float* bias2, void* outp)
{
    constexpr int NCH = K / 32;
    constexpr long NROWS = (MODE == 0 || MODE == 2) ? NN : NE;

    __shared__ alignas(16) u16 Xs[128 * 40];    // 10.2 KB
    __shared__ alignas(16) u16 Ws[128 * 40];    // 10.2 KB
    __shared__ alignas(16) u16 Hs[128 * 136];   // 34.8 KB
    __shared__ int   sIdx[128];
    __shared__ int   tIdx[128];
    __shared__ float part[256];
    __shared__ float w2s[128];

    const int tid  = threadIdx.x;
    const int lane = tid & 63;
    const int wave = tid >> 6;
    const int wm   = wave >> 1;
    const int wn   = wave & 1;
    const int lr   = lane & 15;
    const int lq   = lane >> 4;
    const long tile0 = (long)blockIdx.x * 128;

    if (MODE == 1 || MODE == 3 || MODE == 4) {
        const int is64 = idxFlag[0];
        if (tid < 128) {
            long p = tile0 + tid; if (p > NE - 1) p = NE - 1;
            sIdx[tid] = load_idx(ei, p, is64);
        } else {
            int r = tid - 128;
            long p = tile0 + r; if (p > NE - 1) p = NE - 1;
            tIdx[r] = load_idx(ei, (long)NE + p, is64);
        }
    }
    if (MODE == 4 && tid < 128) w2s[tid] = w2orb2[tid];

    // ---------------- layer 1 ----------------
    f32x4 acc[4][4];
    #pragma unroll
    for (int nt = 0; nt < 4; ++nt) {
        float bv = b1[wn * 64 + nt * 16 + lr];
        #pragma unroll
        for (int mt = 0; mt < 4; ++mt) acc[mt][nt] = (f32x4){bv, bv, bv, bv};
    }

    for (int ch = 0; ch < NCH; ++ch) {
        __syncthreads();
        for (int f = tid; f < 512; f += TPB) {
            int  r = f >> 2, q = f & 3;
            int  k = ch * 32 + q * 8;
            long row = tile0 + r; if (row > NROWS - 1) row = NROWS - 1;
            uint4 v;
            if (MODE == 0) {
                if (q < 2) {
                    const float* s = &fin[row * 16 + q * 8];
                    float4 f0 = *(const float4*)s;
                    float4 f1 = *(const float4*)(s + 4);
                    alignas(16) u16 t[8];
                    t[0]=f2bf(f0.x); t[1]=f2bf(f0.y); t[2]=f2bf(f0.z); t[3]=f2bf(f0.w);
                    t[4]=f2bf(f1.x); t[5]=f2bf(f1.y); t[6]=f2bf(f1.z); t[7]=f2bf(f1.w);
                    v = *(const uint4*)t;
                } else {
                    v = (uint4){0u, 0u, 0u, 0u};
                }
            } else if (MODE == 2) {
                if (k < D) {
                    v = *(const uint4*)&hbuf[row * D + k];
                } else {
                    const float* s = &fin[row * D + (k - D)];
                    float4 f0 = *(const float4*)s;
                    float4 f1 = *(const float4*)(s + 4);
                    alignas(16) u16 t[8];
                    t[0]=f2bf(f0.x); t[1]=f2bf(f0.y); t[2]=f2bf(f0.z); t[3]=f2bf(f0.w);
                    t[4]=f2bf(f1.x); t[5]=f2bf(f1.y); t[6]=f2bf(f1.z); t[7]=f2bf(f1.w);
                    v = *(const uint4*)t;
                }
            } else {
                const u16* s = (k < D)     ? &hbuf[(long)sIdx[r] * D + k]
                             : (k < 2 * D) ? &hbuf[(long)tIdx[r] * D + (k - D)]
                                           : &ebuf[row * D + (k - 2 * D)];
                v = *(const uint4*)s;
            }
            *(uint4*)&Xs[r * 40 + q * 8] = v;
        }
        {
            const uint4* src = (const uint4*)(W1t + (size_t)ch * 5120);
            uint4* dst = (uint4*)Ws;
            for (int f = tid; f < 640; f += TPB) dst[f] = src[f];
        }
        __syncthreads();

        bf16x8 a[4], b[4];
        #pragma unroll
        for (int mt = 0; mt < 4; ++mt)
            a[mt] = *(const bf16x8*)&Xs[(wm * 64 + mt * 16 + lr) * 40 + lq * 8];
        #pragma unroll
        for (int nt = 0; nt < 4; ++nt)
            b[nt] = *(const bf16x8*)&Ws[(wn * 64 + nt * 16 + lr) * 40 + lq * 8];
        #pragma unroll
        for (int mt = 0; mt < 4; ++mt)
            #pragma unroll
            for (int nt = 0; nt < 4; ++nt)
                acc[mt][nt] = __builtin_amdgcn_mfma_f32_16x16x32_bf16(
                                  a[mt], b[nt], acc[mt][nt], 0, 0, 0);
    }

    // relu -> Hs (C layout: col=lane&15, row=(lane>>4)*4+reg)
    #pragma unroll
    for (int mt = 0; mt < 4; ++mt)
        #pragma unroll
        for (int nt = 0; nt < 4; ++nt)
            #pragma unroll
            for (int reg = 0; reg < 4; ++reg) {
                int row = wm * 64 + mt * 16 + lq * 4 + reg;
                int col = wn * 64 + nt * 16 + lr;
                Hs[row * 136 + col] = f2bf(fmaxf(acc[mt][nt][reg], 0.f));
            }
    __syncthreads();

    // ---------------- layer 2 ----------------
    if (MODE == 4) {               // 128 -> 1 head
        float s = 0.f;
        int r = tid >> 1, k0 = (tid & 1) * 64;
        #pragma unroll
        for (int j = 0; j < 64; ++j)
            s += bf2f(Hs[r * 136 + k0 + j]) * w2s[k0 + j];
        part[tid] = s;
        __syncthreads();
        if (tid < 128) {
            long row = tile0 + tid;
            if (row < NROWS)
                ((float*)outp)[row] = part[tid * 2] + part[tid * 2 + 1] + bias2[0];
        }
        return;
    }

    f32x4 acc2[4][4];
    #pragma unroll
    for (int nt = 0; nt < 4; ++nt) {
        float bv = w2orb2[wn * 64 + nt * 16 + lr];
        #pragma unroll
        for (int mt = 0; mt < 4; ++mt) acc2[mt][nt] = (f32x4){bv, bv, bv, bv};
    }
    for (int ch = 0; ch < 4; ++ch) {
        __syncthreads();
        {
            const uint4* src = (const uint4*)(W2t + (size_t)ch * 5120);
            uint4* dst = (uint4*)Ws;
            for (int f = tid; f < 640; f += TPB) dst[f] = src[f];
        }
        __syncthreads();
        bf16x8 a[4], b[4];
        #pragma unroll
        for (int mt = 0; mt < 4; ++mt)
            a[mt] = *(const bf16x8*)&Hs[(wm * 64 + mt * 16 + lr) * 136 + ch * 32 + lq * 8];
        #pragma unroll
        for (int nt = 0; nt < 4; ++nt)
            b[nt] = *(const bf16x8*)&Ws[(wn * 64 + nt * 16 + lr) * 40 + lq * 8];
        #pragma unroll
        for (int mt = 0; mt < 4; ++mt)
            #pragma unroll
            for (int nt = 0; nt < 4; ++nt)
                acc2[mt][nt] = __builtin_amdgcn_mfma_f32_16x16x32_bf16(
                                   a[mt], b[nt], acc2[mt][nt], 0, 0, 0);
    }
    __syncthreads();
    #pragma unroll
    for (int mt = 0; mt < 4; ++mt)
        #pragma unroll
        for (int nt = 0; nt < 4; ++nt)
            #pragma unroll
            for (int reg = 0; reg < 4; ++reg) {
                int row = wm * 64 + mt * 16 + lq * 4 + reg;
                int col = wn * 64 + nt * 16 + lr;
                Hs[row * 136 + col] = f2bf(acc2[mt][nt][reg]);
            }
    __syncthreads();

    // residual + coalesced store
    u16* out = (u16*)outp;
    for (int f = tid; f < 1024; f += TPB) {
        int r = f >> 3, q = f & 7;
        long row = tile0 + r;
        if (row >= NROWS) continue;
        int col = q * 16;
        const u16* hp = &Hs[r * 136 + col];
        alignas(16) u16 ov[16];
        if (MODE == 2 || MODE == 3) {
            const u16* res = (MODE == 3) ? &ebuf[row * D + col] : &hbuf[row * D + col];
            #pragma unroll
            for (int j = 0; j < 16; ++j) ov[j] = f2bf(bf2f(hp[j]) + bf2f(res[j]));
        } else {
            #pragma unroll
            for (int j = 0; j < 16; ++j) ov[j] = hp[j];
        }
        *(uint4*)&out[row * D + col]     = *(const uint4*)&ov[0];
        *(uint4*)&out[row * D + col + 8] = *(const uint4*)&ov[8];
    }
}

// --------------------------- plain kernel symbols ---------------------------

__global__ void k_detect(const int* __restrict__ ei, int* __restrict__ flag) {
    if (threadIdx.x == 0 && blockIdx.x == 0) {
        int any = 0;
        for (int i = 0; i < 64; ++i) any |= ei[2 * i + 1];
        flag[0] = (any == 0) ? 1 : 0;
    }
}

// W [K][128] fp32 -> chunk-blocked transposed bf16 [ch][n=128][k=40pad]
__global__ void k_prep(const float* __restrict__ W, u16* __restrict__ dst,
                       int nch, int Kreal) {
    int total = nch * 5120;
    for (int i = blockIdx.x * TPB + threadIdx.x; i < total; i += gridDim.x * TPB) {
        int ch = i / 5120, rem = i % 5120;
        int n = rem / 40, kk = rem % 40;
        int kr = ch * 32 + kk;
        float v = (kk < 32 && kr < Kreal) ? W[(size_t)kr * 128 + n] : 0.f;
        dst[i] = f2bf(v);
    }
}

// ---- CSR build ----
__global__ void k_hist(const int* __restrict__ ei, const int* __restrict__ flag,
                       int* __restrict__ deg) {
    int i = blockIdx.x * TPB + threadIdx.x;
    if (i < NE) atomicAdd(&deg[load_idx(ei, (long)NE + i, flag[0])], 1);
}

__global__ void k_scanA(const int* __restrict__ deg, int* __restrict__ rp,
                        int* __restrict__ bsum) {
    __shared__ int s[256];
    int t = threadIdx.x, gi = blockIdx.x * 256 + t;
    s[t] = (gi < NN) ? deg[gi] : 0;
    for (int off = 1; off < 256; off <<= 1) {
        __syncthreads();
        int v = (t >= off) ? s[t - off] : 0;
        __syncthreads();
        s[t] += v;
    }
    __syncthreads();
    if (gi < NN) rp[gi] = s[t];          // inclusive, block-local
    if (t == 255) bsum[blockIdx.x] = s[255];
}

__global__ void k_scanB(int* __restrict__ bsum, int* __restrict__ boff, int nb) {
    if (threadIdx.x == 0 && blockIdx.x == 0) {
        int run = 0;
        for (int b = 0; b < nb; ++b) { boff[b] = run; run += bsum[b]; }
    }
}

__global__ void k_scanC(const int* __restrict__ deg, int* __restrict__ rp,
                        const int* __restrict__ boff) {
    int t = threadIdx.x, gi = blockIdx.x * 256 + t;
    if (gi >= NN) return;
    int incl = rp[gi] + boff[blockIdx.x];
    rp[gi] = incl - deg[gi];             // exclusive with block offset
    if (gi == NN - 1) rp[NN] = incl;
}

__global__ void k_fill(const int* __restrict__ ei, const int* __restrict__ flag,
                       int* __restrict__ cursor, int* __restrict__ eids) {
    int i = blockIdx.x * TPB + threadIdx.x;
    if (i >= NE) return;
    int n = load_idx(ei, (long)NE + i, flag[0]);
    int pos = atomicAdd(&cursor[n], 1);
    eids[pos] = i;
}

// msg[n] = sum over incoming edges of e[edge]  (one wave per node)
__global__ void k_gather(const u16* __restrict__ e, const int* __restrict__ rp,
                         const int* __restrict__ eids, float* __restrict__ msg) {
    int node = blockIdx.x * 4 + (threadIdx.x >> 6);
    if (node >= NN) return;
    int lane = threadIdx.x & 63;
    int beg = rp[node], end = rp[node + 1];
    float a0 = 0.f, a1 = 0.f;
    for (int i = beg; i < end; ++i) {
        unsigned v = ((const unsigned*)e)[(size_t)eids[i] * 64 + lane];
        a0 += bf2f((u16)(v & 0xffff));
        a1 += bf2f((u16)(v >> 16));
    }
    float2 o; o.x = a0; o.y = a1;
    *(float2*)&msg[(size_t)node * 128 + lane * 2] = o;
}

// ---- MLP kernel wrappers ----
__launch_bounds__(TPB)
__global__ void k_node_enc_m(const float* nodes, const u16* W1t, const float* b1,
                             const u16* W2t, const float* b2, u16* h) {
    mfma_mlp<32, 0>(nullptr, nullptr, nodes, nullptr, nullptr, W1t, b1, W2t, b2, nullptr, h);
}
__launch_bounds__(TPB)
__global__ void k_edge_enc_m(const u16* h, const int* ei, const int* flag,
                             const u16* W1t, const float* b1,
                             const u16* W2t, const float* b2, u16* e) {
    mfma_mlp<256, 1>(h, nullptr, nullptr, ei, flag, W1t, b1, W2t, b2, nullptr, e);
}
__launch_bounds__(TPB)
__global__ void k_node_upd_m(const u16* h, const float* msg,
                             const u16* W1t, const float* b1,
                             const u16* W2t, const float* b2, u16* hout) {
    mfma_mlp<256, 2>(h, nullptr, msg, nullptr, nullptr, W1t, b1, W2t, b2, nullptr, hout);
}
__launch_bounds__(TPB)
__global__ void k_edge_upd_m(const u16* h, const u16* e, const int* ei, const int* flag,
                             const u16* W1t, const float* b1,
                             const u16* W2t, const float* b2, u16* eout) {
    mfma_mlp<384, 3>(h, e, nullptr, ei, flag, W1t, b1, W2t, b2, nullptr, eout);
}
__launch_bounds__(TPB)
__global__ void k_decode_m(const u16* h, const u16* e, const int* ei, const int* flag,
                           const u16* W1t, const float* b1,
                           const float* w2, const float* b2, float* pred) {
    mfma_mlp<384, 4>(h, e, nullptr, ei, flag, W1t, b1, nullptr, w2, b2, pred);
}

// ---------------------------------------------------------------------------

extern "C" void kernel_launch(void* const* d_in, const int* in_sizes, int n_in,
                              void* d_out, int out_size, void* d_ws, size_t ws_size,
                              hipStream_t stream)
{
    const float* nodes = (const float*)d_in[0];
    const int*   ei    = (const int*)d_in[1];
    const float* ne_W1 = (const float*)d_in[2];  const float* ne_b1 = (const float*)d_in[3];
    const float* ne_W2 = (const float*)d_in[4];  const float* ne_b2 = (const float*)d_in[5];
    const float* ee_W1 = (const float*)d_in[6];  const float* ee_b1 = (const float*)d_in[7];
    const float* ee_W2 = (const float*)d_in[8];  const float* ee_b2 = (const float*)d_in[9];
    const float* nn_W1 = (const float*)d_in[10]; const float* nn_b1 = (const float*)d_in[11];
    const float* nn_W2 = (const float*)d_in[12]; const float* nn_b2 = (const float*)d_in[13];
    const float* en_W1 = (const float*)d_in[14]; const float* en_b1 = (const float*)d_in[15];
    const float* en_W2 = (const float*)d_in[16]; const float* en_b2 = (const float*)d_in[17];
    const float* pe_W1 = (const float*)d_in[18]; const float* pe_b1 = (const float*)d_in[19];
    const float* pe_W2 = (const float*)d_in[20]; const float* pe_b2 = (const float*)d_in[21];

    const size_t hN = (size_t)NN * D;
    const size_t eN = (size_t)NE * D;
    const int NB = (NN + 255) / 256;    // 391 scan blocks

    // weight chunk counts: ne1(1) ne2(4) ee1(8) ee2(4) nn1(8) nn2(4) en1(12) en2(4) pe1(12)
    const size_t wTot = (size_t)(1 + 4 + 8 + 4 + 8 + 4 + 12 + 4 + 12) * 5120;  // u16

    const size_t need = 256 + hN * 2 + eN * 2 + hN * 4 + wTot * 2
                      + (size_t)NN * 4            // deg
                      + (size_t)(NN + 1) * 4      // row_ptr
                      + (size_t)NN * 4            // cursor
                      + (size_t)NE * 4            // eids
                      + 1024 * 4;                 // bsum+boff
    if (ws_size < need) {
        hipMemsetAsync(d_out, 0x43, (size_t)out_size * sizeof(float), stream);
        return;
    }

    char* p = (char*)d_ws;
    int*   flag  = (int*)p;                   p += 256;
    u16*   h     = (u16*)p;                   p += hN * 2;
    u16*   e     = (u16*)p;                   p += eN * 2;
    float* msg   = (float*)p;                 p += hN * 4;
    float* stage = msg;                       // overlaps msg (dead at decode)
    u16*   ne1t  = (u16*)p;                   p += (size_t)1  * 5120 * 2;
    u16*   ne2t  = (u16*)p;                   p += (size_t)4  * 5120 * 2;
    u16*   ee1t  = (u16*)p;                   p += (size_t)8  * 5120 * 2;
    u16*   ee2t  = (u16*)p;                   p += (size_t)4  * 5120 * 2;
    u16*   nn1t  = (u16*)p;                   p += (size_t)8  * 5120 * 2;
    u16*   nn2t  = (u16*)p;                   p += (size_t)4  * 5120 * 2;
    u16*   en1t  = (u16*)p;                   p += (size_t)12 * 5120 * 2;
    u16*   en2t  = (u16*)p;                   p += (size_t)4  * 5120 * 2;
    u16*   pe1t  = (u16*)p;                   p += (size_t)12 * 5120 * 2;
    int*   deg   = (int*)p;                   p += (size_t)NN * 4;
    int*   rp    = (int*)p;                   p += (size_t)(NN + 1) * 4;
    int*   cur   = (int*)p;                   p += (size_t)NN * 4;
    int*   eids  = (int*)p;                   p += (size_t)NE * 4;
    int*   bsum  = (int*)p;                   p += 512 * 4;
    int*   boff  = (int*)p;

    dim3 blk(TPB);
    k_detect<<<1, 64, 0, stream>>>(ei, flag);

    k_prep<<<32, blk, 0, stream>>>(ne_W1, ne1t, 1, 16);
    k_prep<<<32, blk, 0, stream>>>(ne_W2, ne2t, 4, 128);
    k_prep<<<32, blk, 0, stream>>>(ee_W1, ee1t, 8, 256);
    k_prep<<<32, blk, 0, stream>>>(ee_W2, ee2t, 4, 128);
    k_prep<<<32, blk, 0, stream>>>(nn_W1, nn1t, 8, 256);
    k_prep<<<32, blk, 0, stream>>>(nn_W2, nn2t, 4, 128);
    k_prep<<<32, blk, 0, stream>>>(en_W1, en1t, 12, 384);
    k_prep<<<32, blk, 0, stream>>>(en_W2, en2t, 4, 128);
    k_prep<<<32, blk, 0, stream>>>(pe_W1, pe1t, 12, 384);

    // CSR build (per-call; edge_index is an input)
    hipMemsetAsync(deg, 0, (size_t)NN * 4, stream);
    k_hist<<<(NE + TPB - 1) / TPB, blk, 0, stream>>>(ei, flag, deg);
    k_scanA<<<NB, blk, 0, stream>>>(deg, rp, bsum);
    k_scanB<<<1, 64, 0, stream>>>(bsum, boff, NB);
    k_scanC<<<NB, blk, 0, stream>>>(deg, rp, boff);
    hipMemcpyAsync(cur, rp, (size_t)NN * 4, hipMemcpyDeviceToDevice, stream);
    k_fill<<<(NE + TPB - 1) / TPB, blk, 0, stream>>>(ei, flag, cur, eids);

    const int EG = (NE + 127) / 128;    // 4688
    const int NG = (NN + 127) / 128;    // 782

    k_node_enc_m<<<NG, blk, 0, stream>>>(nodes, ne1t, ne_b1, ne2t, ne_b2, h);
    k_edge_enc_m<<<EG, blk, 0, stream>>>(h, ei, flag, ee1t, ee_b1, ee2t, ee_b2, e);

    for (int it = 0; it < 4; ++it) {
        k_gather<<<(NN + 3) / 4, blk, 0, stream>>>(e, rp, eids, msg);
        // e <- MLP_en([h_old[s], h_old[t], e_old]) + e_old   (uses pre-update h)
        k_edge_upd_m<<<EG, blk, 0, stream>>>(h, e, ei, flag, en1t, en_b1, en2t, en_b2, e);
        // h <- MLP_nn([h_old, msg]) + h_old
        k_node_upd_m<<<NG, blk, 0, stream>>>(h, msg, nn1t, nn_b1, nn2t, nn_b2, h);
    }

    k_decode_m<<<EG, blk, 0, stream>>>(h, e, ei, flag, pe1t, pe_b1, pe_W2, pe_b2, stage);
    hipMemcpyAsync(d_out, stage, (size_t)NE * sizeof(float),
                   hipMemcpyDeviceToDevice, stream);
}

// Round 13
// 1639.389 us; speedup vs baseline: 17.7557x; 1.4562x over previous
//
#include <hip/hip_runtime.h>

// InteractionGNN on MI355X — Round 13: barrier-free K-loop MFMA.
// R12 post-mortem: edge MLPs were LDS-pipe-bound (MfmaUtil 9.9%, 52 KB LDS
// traffic per 64 MFMA, 2 barriers/chunk). This round: A- and B-fragments are
// loaded DIRECTLY from global (weights pre-packed frag-major, 1 KB coalesced
// per wave-frag; gathered h rows via register indices), K-loop has NO
// barriers, LDS only holds Hs (layer1->layer2 transform) + indices (~36 KB).
// Pipeline/CSR/gather/msg identical to R12 (proven, absmax 3.9e-3).

#define TPB 256
constexpr int D    = 128;
constexpr int NN   = 100000;
constexpr int NE   = 600000;

typedef unsigned short u16;
typedef __attribute__((ext_vector_type(8))) short bf16x8;
typedef __attribute__((ext_vector_type(4))) float f32x4;

__device__ inline float bf2f(u16 x) { return __uint_as_float((unsigned)x << 16); }
__device__ inline u16 f2bf(float f) {   // round-to-nearest-even
    unsigned u = __float_as_uint(f);
    unsigned r = u + 0x7FFFu + ((u >> 16) & 1u);
    return (u16)(r >> 16);
}
__device__ inline int load_idx(const int* ei, long pos, int is64) {
    int v = is64 ? ei[2 * pos] : ei[pos];
    return (v < 0) ? 0 : (v >= NN ? NN - 1 : v);
}
__device__ inline bf16x8 pack8(float4 f0, float4 f1) {
    union { bf16x8 v; u16 t[8]; } u;
    u.t[0] = f2bf(f0.x); u.t[1] = f2bf(f0.y); u.t[2] = f2bf(f0.z); u.t[3] = f2bf(f0.w);
    u.t[4] = f2bf(f1.x); u.t[5] = f2bf(f1.y); u.t[6] = f2bf(f1.z); u.t[7] = f2bf(f1.w);
    return u.v;
}
__device__ inline bf16x8 zero8() {
    union { bf16x8 v; u16 t[8]; } u;
    #pragma unroll
    for (int j = 0; j < 8; ++j) u.t[j] = 0;
    return u.v;
}

// ---------------------------------------------------------------------------
// Barrier-free MFMA MLP. Block tile M=128 x N=128; 4 waves 2x2; wave 64x64.
// MODE: 0 node-enc (K=32 pad, fin fp32[*,16]) | 1 edge-enc (K=256, [h_s,h_t])
//       2 node-upd (K=256, [h, msg fp32], +h) | 3 edge-upd (K=384, [h_s,h_t,e], +e)
//       4 decoder  (K=384, layer2 128->1, fp32 out)
// W1f/W2f: frag-major packed bf16: idx = ((ch*2+wn)*4+nt)*512 + lane*8.
// ---------------------------------------------------------------------------
template<int K, int MODE>
__device__ inline void mfma2(const u16* hbuf, const u16* ebuf, const float* fin,
                             const int* ei, const int* idxFlag,
                             const u16* __restrict__ W1f, const float* b1,
                             const u16* __restrict__ W2f, const float* w2orb2,
                             const float* bias2, void* outp)
{
    constexpr int NCH = K / 32;
    constexpr long NROWS = (MODE == 0 || MODE == 2) ? NN : NE;

    __shared__ alignas(16) u16 Hs[128 * 136];   // 34.8 KB
    __shared__ int   sIdx[128];
    __shared__ int   tIdx[128];
    __shared__ float part[256];
    __shared__ float w2s[128];

    const int tid  = threadIdx.x;
    const int lane = tid & 63;
    const int wave = tid >> 6;
    const int wm   = wave >> 1;
    const int wn   = wave & 1;
    const int lr   = lane & 15;
    const int lq   = lane >> 4;
    const long tile0 = (long)blockIdx.x * 128;

    if (MODE == 1 || MODE == 3 || MODE == 4) {
        const int is64 = idxFlag[0];
        if (tid < 128) {
            long p = tile0 + tid; if (p > NE - 1) p = NE - 1;
            sIdx[tid] = load_idx(ei, p, is64);
        } else {
            int r = tid - 128;
            long p = tile0 + r; if (p > NE - 1) p = NE - 1;
            tIdx[r] = load_idx(ei, (long)NE + p, is64);
        }
        if (MODE == 4 && tid < 128) w2s[tid] = w2orb2[tid];
        __syncthreads();
    } else if (MODE == 4) {
        if (tid < 128) w2s[tid] = w2orb2[tid];
    }

    // per-lane row constants (hoisted out of the K-loop)
    long grow[4]; int si[4], ti[4];
    #pragma unroll
    for (int mt = 0; mt < 4; ++mt) {
        int rloc = wm * 64 + mt * 16 + lr;
        long g = tile0 + rloc; if (g > NROWS - 1) g = NROWS - 1;
        grow[mt] = g;
        if (MODE == 1 || MODE == 3 || MODE == 4) { si[mt] = sIdx[rloc]; ti[mt] = tIdx[rloc]; }
    }

    // ---------------- layer 1 (barrier-free K-loop) ----------------
    f32x4 acc[4][4];
    #pragma unroll
    for (int nt = 0; nt < 4; ++nt) {
        float bv = b1[wn * 64 + nt * 16 + lr];
        #pragma unroll
        for (int mt = 0; mt < 4; ++mt) acc[mt][nt] = (f32x4){bv, bv, bv, bv};
    }

    #pragma unroll
    for (int ch = 0; ch < NCH; ++ch) {
        const int k = ch * 32 + lq * 8;
        bf16x8 a[4], b[4];
        #pragma unroll
        for (int mt = 0; mt < 4; ++mt) {
            if (MODE == 0) {
                if (lq < 2) {
                    const float* s = &fin[grow[mt] * 16 + lq * 8];
                    a[mt] = pack8(*(const float4*)s, *(const float4*)(s + 4));
                } else a[mt] = zero8();
            } else if (MODE == 1) {
                const u16* s = (k < 128) ? &hbuf[(long)si[mt] * 128 + k]
                                         : &hbuf[(long)ti[mt] * 128 + (k - 128)];
                a[mt] = *(const bf16x8*)s;
            } else if (MODE == 2) {
                if (k < 128) {
                    a[mt] = *(const bf16x8*)&hbuf[grow[mt] * 128 + k];
                } else {
                    const float* s = &fin[grow[mt] * 128 + (k - 128)];
                    a[mt] = pack8(*(const float4*)s, *(const float4*)(s + 4));
                }
            } else {
                const u16* s = (k < 128)  ? &hbuf[(long)si[mt] * 128 + k]
                             : (k < 256)  ? &hbuf[(long)ti[mt] * 128 + (k - 128)]
                                          : &ebuf[grow[mt] * 128 + (k - 256)];
                a[mt] = *(const bf16x8*)s;
            }
        }
        #pragma unroll
        for (int nt = 0; nt < 4; ++nt)
            b[nt] = *(const bf16x8*)&W1f[(size_t)(((ch * 2 + wn) * 4 + nt) * 512) + lane * 8];
        #pragma unroll
        for (int mt = 0; mt < 4; ++mt)
            #pragma unroll
            for (int nt = 0; nt < 4; ++nt)
                acc[mt][nt] = __builtin_amdgcn_mfma_f32_16x16x32_bf16(
                                  a[mt], b[nt], acc[mt][nt], 0, 0, 0);
    }

    // relu -> Hs (C layout: col=lane&15, row=(lane>>4)*4+reg)
    #pragma unroll
    for (int mt = 0; mt < 4; ++mt)
        #pragma unroll
        for (int nt = 0; nt < 4; ++nt)
            #pragma unroll
            for (int reg = 0; reg < 4; ++reg) {
                int row = wm * 64 + mt * 16 + lq * 4 + reg;
                int col = wn * 64 + nt * 16 + lr;
                Hs[row * 136 + col] = f2bf(fmaxf(acc[mt][nt][reg], 0.f));
            }
    __syncthreads();

    // ---------------- layer 2 ----------------
    if (MODE == 4) {               // 128 -> 1 head
        float s = 0.f;
        int r = tid >> 1, k0 = (tid & 1) * 64;
        #pragma unroll
        for (int j = 0; j < 64; ++j)
            s += bf2f(Hs[r * 136 + k0 + j]) * w2s[k0 + j];
        part[tid] = s;
        __syncthreads();
        if (tid < 128) {
            long row = tile0 + tid;
            if (row < NROWS)
                ((float*)outp)[row] = part[tid * 2] + part[tid * 2 + 1] + bias2[0];
        }
        return;
    }

    f32x4 acc2[4][4];
    #pragma unroll
    for (int nt = 0; nt < 4; ++nt) {
        float bv = w2orb2[wn * 64 + nt * 16 + lr];
        #pragma unroll
        for (int mt = 0; mt < 4; ++mt) acc2[mt][nt] = (f32x4){bv, bv, bv, bv};
    }
    #pragma unroll
    for (int ch = 0; ch < 4; ++ch) {
        bf16x8 a[4], b[4];
        #pragma unroll
        for (int mt = 0; mt < 4; ++mt)
            a[mt] = *(const bf16x8*)&Hs[(wm * 64 + mt * 16 + lr) * 136 + ch * 32 + lq * 8];
        #pragma unroll
        for (int nt = 0; nt < 4; ++nt)
            b[nt] = *(const bf16x8*)&W2f[(size_t)(((ch * 2 + wn) * 4 + nt) * 512) + lane * 8];
        #pragma unroll
        for (int mt = 0; mt < 4; ++mt)
            #pragma unroll
            for (int nt = 0; nt < 4; ++nt)
                acc2[mt][nt] = __builtin_amdgcn_mfma_f32_16x16x32_bf16(
                                   a[mt], b[nt], acc2[mt][nt], 0, 0, 0);
    }
    __syncthreads();               // all Hs reads done before overwrite
    #pragma unroll
    for (int mt = 0; mt < 4; ++mt)
        #pragma unroll
        for (int nt = 0; nt < 4; ++nt)
            #pragma unroll
            for (int reg = 0; reg < 4; ++reg) {
                int row = wm * 64 + mt * 16 + lq * 4 + reg;
                int col = wn * 64 + nt * 16 + lr;
                Hs[row * 136 + col] = f2bf(acc2[mt][nt][reg]);
            }
    __syncthreads();

    // residual + coalesced store
    u16* out = (u16*)outp;
    for (int f = tid; f < 1024; f += TPB) {
        int r = f >> 3, q = f & 7;
        long row = tile0 + r;
        if (row >= NROWS) continue;
        int col = q * 16;
        const u16* hp = &Hs[r * 136 + col];
        alignas(16) u16 ov[16];
        if (MODE == 2 || MODE == 3) {
            const u16* res = (MODE == 3) ? &ebuf[row * D + col] : &hbuf[row * D + col];
            #pragma unroll
            for (int j = 0; j < 16; ++j) ov[j] = f2bf(bf2f(hp[j]) + bf2f(res[j]));
        } else {
            #pragma unroll
            for (int j = 0; j < 16; ++j) ov[j] = hp[j];
        }
        *(uint4*)&out[row * D + col]     = *(const uint4*)&ov[0];
        *(uint4*)&out[row * D + col + 8] = *(const uint4*)&ov[8];
    }
}

// --------------------------- plain kernel symbols ---------------------------

__global__ void k_detect(const int* __restrict__ ei, int* __restrict__ flag) {
    if (threadIdx.x == 0 && blockIdx.x == 0) {
        int any = 0;
        for (int i = 0; i < 64; ++i) any |= ei[2 * i + 1];
        flag[0] = (any == 0) ? 1 : 0;
    }
}

// W [K][128] fp32 -> frag-major bf16: idx=((ch*2+wn)*4+nt)*512+lane*8+j
// value = W[ch*32+(lane>>4)*8+j][wn*64+nt*16+(lane&15)]
__global__ void k_prep2(const float* __restrict__ W, u16* __restrict__ dst,
                        int nch, int Kreal) {
    int total = nch * 4096;
    for (int i = blockIdx.x * TPB + threadIdx.x; i < total; i += gridDim.x * TPB) {
        int j    = i & 7;
        int lane = (i >> 3) & 63;
        int nt   = (i >> 9) & 3;
        int wnn  = (i >> 11) & 1;
        int ch   = i >> 12;
        int k = ch * 32 + (lane >> 4) * 8 + j;
        int n = wnn * 64 + nt * 16 + (lane & 15);
        dst[i] = f2bf((k < Kreal) ? W[(size_t)k * 128 + n] : 0.f);
    }
}

// ---- CSR build ----
__global__ void k_hist(const int* __restrict__ ei, const int* __restrict__ flag,
                       int* __restrict__ deg) {
    int i = blockIdx.x * TPB + threadIdx.x;
    if (i < NE) atomicAdd(&deg[load_idx(ei, (long)NE + i, flag[0])], 1);
}
__global__ void k_scanA(const int* __restrict__ deg, int* __restrict__ rp,
                        int* __restrict__ bsum) {
    __shared__ int s[256];
    int t = threadIdx.x, gi = blockIdx.x * 256 + t;
    s[t] = (gi < NN) ? deg[gi] : 0;
    for (int off = 1; off < 256; off <<= 1) {
        __syncthreads();
        int v = (t >= off) ? s[t - off] : 0;
        __syncthreads();
        s[t] += v;
    }
    __syncthreads();
    if (gi < NN) rp[gi] = s[t];
    if (t == 255) bsum[blockIdx.x] = s[255];
}
__global__ void k_scanB(int* __restrict__ bsum, int* __restrict__ boff, int nb) {
    if (threadIdx.x == 0 && blockIdx.x == 0) {
        int run = 0;
        for (int b = 0; b < nb; ++b) { boff[b] = run; run += bsum[b]; }
    }
}
__global__ void k_scanC(const int* __restrict__ deg, int* __restrict__ rp,
                        const int* __restrict__ boff) {
    int t = threadIdx.x, gi = blockIdx.x * 256 + t;
    if (gi >= NN) return;
    int incl = rp[gi] + boff[blockIdx.x];
    rp[gi] = incl - deg[gi];
    if (gi == NN - 1) rp[NN] = incl;
}
__global__ void k_fill(const int* __restrict__ ei, const int* __restrict__ flag,
                       int* __restrict__ cursor, int* __restrict__ eids) {
    int i = blockIdx.x * TPB + threadIdx.x;
    if (i >= NE) return;
    int n = load_idx(ei, (long)NE + i, flag[0]);
    int pos = atomicAdd(&cursor[n], 1);
    eids[pos] = i;
}

// msg[n] = sum over incoming edges of e[edge]  (one wave per node)
__global__ void k_gather(const u16* __restrict__ e, const int* __restrict__ rp,
                         const int* __restrict__ eids, float* __restrict__ msg) {
    int node = blockIdx.x * 4 + (threadIdx.x >> 6);
    if (node >= NN) return;
    int lane = threadIdx.x & 63;
    int beg = rp[node], end = rp[node + 1];
    float a0 = 0.f, a1 = 0.f;
    for (int i = beg; i < end; ++i) {
        unsigned v = ((const unsigned*)e)[(size_t)eids[i] * 64 + lane];
        a0 += bf2f((u16)(v & 0xffff));
        a1 += bf2f((u16)(v >> 16));
    }
    float2 o; o.x = a0; o.y = a1;
    *(float2*)&msg[(size_t)node * 128 + lane * 2] = o;
}

// ---- MLP kernel wrappers ----
__launch_bounds__(TPB)
__global__ void k_node_enc2(const float* nodes, const u16* W1f, const float* b1,
                            const u16* W2f, const float* b2, u16* h) {
    mfma2<32, 0>(nullptr, nullptr, nodes, nullptr, nullptr, W1f, b1, W2f, b2, nullptr, h);
}
__launch_bounds__(TPB)
__global__ void k_edge_enc2(const u16* h, const int* ei, const int* flag,
                            const u16* W1f, const float* b1,
                            const u16* W2f, const float* b2, u16* e) {
    mfma2<256, 1>(h, nullptr, nullptr, ei, flag, W1f, b1, W2f, b2, nullptr, e);
}
__launch_bounds__(TPB)
__global__ void k_node_upd2(const u16* h, const float* msg,
                            const u16* W1f, const float* b1,
                            const u16* W2f, const float* b2, u16* hout) {
    mfma2<256, 2>(h, nullptr, msg, nullptr, nullptr, W1f, b1, W2f, b2, nullptr, hout);
}
__launch_bounds__(TPB)
__global__ void k_edge_upd2(const u16* h, const u16* e, const int* ei, const int* flag,
                            const u16* W1f, const float* b1,
                            const u16* W2f, const float* b2, u16* eout) {
    mfma2<384, 3>(h, e, nullptr, ei, flag, W1f, b1, W2f, b2, nullptr, eout);
}
__launch_bounds__(TPB)
__global__ void k_decode2(const u16* h, const u16* e, const int* ei, const int* flag,
                          const u16* W1f, const float* b1,
                          const float* w2, const float* b2, float* pred) {
    mfma2<384, 4>(h, e, nullptr, ei, flag, W1f, b1, nullptr, w2, b2, pred);
}

// ---------------------------------------------------------------------------

extern "C" void kernel_launch(void* const* d_in, const int* in_sizes, int n_in,
                              void* d_out, int out_size, void* d_ws, size_t ws_size,
                              hipStream_t stream)
{
    const float* nodes = (const float*)d_in[0];
    const int*   ei    = (const int*)d_in[1];
    const float* ne_W1 = (const float*)d_in[2];  const float* ne_b1 = (const float*)d_in[3];
    const float* ne_W2 = (const float*)d_in[4];  const float* ne_b2 = (const float*)d_in[5];
    const float* ee_W1 = (const float*)d_in[6];  const float* ee_b1 = (const float*)d_in[7];
    const float* ee_W2 = (const float*)d_in[8];  const float* ee_b2 = (const float*)d_in[9];
    const float* nn_W1 = (const float*)d_in[10]; const float* nn_b1 = (const float*)d_in[11];
    const float* nn_W2 = (const float*)d_in[12]; const float* nn_b2 = (const float*)d_in[13];
    const float* en_W1 = (const float*)d_in[14]; const float* en_b1 = (const float*)d_in[15];
    const float* en_W2 = (const float*)d_in[16]; const float* en_b2 = (const float*)d_in[17];
    const float* pe_W1 = (const float*)d_in[18]; const float* pe_b1 = (const float*)d_in[19];
    const float* pe_W2 = (const float*)d_in[20]; const float* pe_b2 = (const float*)d_in[21];

    const size_t hN = (size_t)NN * D;
    const size_t eN = (size_t)NE * D;
    const int NB = (NN + 255) / 256;

    // frag-pack element counts (u16): K*128 each
    const size_t sNE1 = 32 * 128,  sNE2 = 128 * 128;
    const size_t sEE1 = 256 * 128, sEE2 = 128 * 128;
    const size_t sNN1 = 256 * 128, sNN2 = 128 * 128;
    const size_t sEN1 = 384 * 128, sEN2 = 128 * 128;
    const size_t sPE1 = 384 * 128;
    const size_t wTot = sNE1 + sNE2 + sEE1 + sEE2 + sNN1 + sNN2 + sEN1 + sEN2 + sPE1;

    const size_t need = 256 + hN * 2 + eN * 2 + hN * 4 + wTot * 2
                      + (size_t)NN * 4 + (size_t)(NN + 1) * 4 + (size_t)NN * 4
                      + (size_t)NE * 4 + 1024 * 4;
    if (ws_size < need) {
        hipMemsetAsync(d_out, 0x43, (size_t)out_size * sizeof(float), stream);
        return;
    }

    char* p = (char*)d_ws;
    int*   flag  = (int*)p;                   p += 256;
    u16*   h     = (u16*)p;                   p += hN * 2;
    u16*   e     = (u16*)p;                   p += eN * 2;
    float* msg   = (float*)p;                 p += hN * 4;
    float* stage = msg;                       // overlaps msg (dead at decode)
    u16*   ne1f  = (u16*)p;                   p += sNE1 * 2;
    u16*   ne2f  = (u16*)p;                   p += sNE2 * 2;
    u16*   ee1f  = (u16*)p;                   p += sEE1 * 2;
    u16*   ee2f  = (u16*)p;                   p += sEE2 * 2;
    u16*   nn1f  = (u16*)p;                   p += sNN1 * 2;
    u16*   nn2f  = (u16*)p;                   p += sNN2 * 2;
    u16*   en1f  = (u16*)p;                   p += sEN1 * 2;
    u16*   en2f  = (u16*)p;                   p += sEN2 * 2;
    u16*   pe1f  = (u16*)p;                   p += sPE1 * 2;
    int*   deg   = (int*)p;                   p += (size_t)NN * 4;
    int*   rp    = (int*)p;                   p += (size_t)(NN + 1) * 4;
    int*   cur   = (int*)p;                   p += (size_t)NN * 4;
    int*   eids  = (int*)p;                   p += (size_t)NE * 4;
    int*   bsum  = (int*)p;                   p += 512 * 4;
    int*   boff  = (int*)p;

    dim3 blk(TPB);
    k_detect<<<1, 64, 0, stream>>>(ei, flag);

    k_prep2<<<32, blk, 0, stream>>>(ne_W1, ne1f, 1, 16);
    k_prep2<<<32, blk, 0, stream>>>(ne_W2, ne2f, 4, 128);
    k_prep2<<<32, blk, 0, stream>>>(ee_W1, ee1f, 8, 256);
    k_prep2<<<32, blk, 0, stream>>>(ee_W2, ee2f, 4, 128);
    k_prep2<<<32, blk, 0, stream>>>(nn_W1, nn1f, 8, 256);
    k_prep2<<<32, blk, 0, stream>>>(nn_W2, nn2f, 4, 128);
    k_prep2<<<32, blk, 0, stream>>>(en_W1, en1f, 12, 384);
    k_prep2<<<32, blk, 0, stream>>>(en_W2, en2f, 4, 128);
    k_prep2<<<32, blk, 0, stream>>>(pe_W1, pe1f, 12, 384);

    // CSR build
    hipMemsetAsync(deg, 0, (size_t)NN * 4, stream);
    k_hist<<<(NE + TPB - 1) / TPB, blk, 0, stream>>>(ei, flag, deg);
    k_scanA<<<NB, blk, 0, stream>>>(deg, rp, bsum);
    k_scanB<<<1, 64, 0, stream>>>(bsum, boff, NB);
    k_scanC<<<NB, blk, 0, stream>>>(deg, rp, boff);
    hipMemcpyAsync(cur, rp, (size_t)NN * 4, hipMemcpyDeviceToDevice, stream);
    k_fill<<<(NE + TPB - 1) / TPB, blk, 0, stream>>>(ei, flag, cur, eids);

    const int EG = (NE + 127) / 128;    // 4688
    const int NG = (NN + 127) / 128;    // 782

    k_node_enc2<<<NG, blk, 0, stream>>>(nodes, ne1f, ne_b1, ne2f, ne_b2, h);
    k_edge_enc2<<<EG, blk, 0, stream>>>(h, ei, flag, ee1f, ee_b1, ee2f, ee_b2, e);

    for (int it = 0; it < 4; ++it) {
        k_gather<<<(NN + 3) / 4, blk, 0, stream>>>(e, rp, eids, msg);
        // e <- MLP_en([h_old[s], h_old[t], e_old]) + e_old   (uses pre-update h)
        k_edge_upd2<<<EG, blk, 0, stream>>>(h, e, ei, flag, en1f, en_b1, en2f, en_b2, e);
        // h <- MLP_nn([h_old, msg]) + h_old
        k_node_upd2<<<NG, blk, 0, stream>>>(h, msg, nn1f, nn_b1, nn2f, nn_b2, h);
    }

    k_decode2<<<EG, blk, 0, stream>>>(h, e, ei, flag, pe1f, pe_b1, pe_W2, pe_b2, stage);
    hipMemcpyAsync(d_out, stage, (size_t)NE * sizeof(float),
                   hipMemcpyDeviceToDevice, stream);
}